// Round 3
// baseline (158.625 us; speedup 1.0000x reference)
//
#include <hip/hip_runtime.h>
#include <math.h>

#define EPSILON 0.3f
#define ALPHA 0.7f
#define LN_EPS 1e-5f

typedef __bf16 bf16x8 __attribute__((ext_vector_type(8)));
typedef float f32x4 __attribute__((ext_vector_type(4)));

__device__ __forceinline__ unsigned short f2bf(float f) {
  unsigned int u = __float_as_uint(f);
  return (unsigned short)((u + 0x7fffu + ((u >> 16) & 1u)) >> 16);
}
__device__ __forceinline__ unsigned int pack2(float lo, float hi) {
  return (unsigned int)f2bf(lo) | ((unsigned int)f2bf(hi) << 16);
}

// async 16B/lane global->LDS DMA; lds base wave-uniform (HW adds lane*16)
__device__ __forceinline__ void async16(const unsigned short* g,
                                        unsigned short* l) {
  __builtin_amdgcn_global_load_lds(
      (const __attribute__((address_space(1))) unsigned int*)g,
      (__attribute__((address_space(3))) unsigned int*)l, 16, 0, 0);
}

__device__ __forceinline__ float wave_reduce(float v) {
#pragma unroll
  for (int off = 32; off > 0; off >>= 1) v += __shfl_xor(v, off, 64);
  return v;
}

__device__ __forceinline__ float blk_reduce_sum(float v, float* red) {
  v = wave_reduce(v);
  int lane = threadIdx.x & 63, wid = threadIdx.x >> 6;
  __syncthreads();
  if (lane == 0) red[wid] = v;
  __syncthreads();
  return red[0] + red[1] + red[2] + red[3];
}

// Grid barrier, RMW-free polling. Arrival counters distributed over 8
// cachelines (bid&7) so the 512 arrival fetch_adds serialize only 64-deep
// per line. Pollers use atomic LOADS (no RMW storm at the coherence point).
// Counters zeroed host-side (in-graph memsetAsync) each run; each barrier
// slot used exactly once per kernel execution.
__device__ __forceinline__ void gridbar(int* base, int nBlk, int bid) {
  __syncthreads();  // all threads' stores issued
  if (threadIdx.x == 0) {
    __threadfence();  // release: drain stores to coherence point
    __hip_atomic_fetch_add(base + (bid & 7) * 32, 1, __ATOMIC_RELAXED,
                           __HIP_MEMORY_SCOPE_AGENT);
    int iters = 0;
    for (;;) {
      int sum = 0;
#pragma unroll
      for (int i = 0; i < 8; ++i)
        sum += __hip_atomic_load(base + i * 32, __ATOMIC_RELAXED,
                                 __HIP_MEMORY_SCOPE_AGENT);
      if (sum >= nBlk) break;
      __builtin_amdgcn_s_sleep(4);
      if (++iters > (1 << 20)) break;  // livelock failsafe -> fail, not hang
    }
    __threadfence();  // acquire
  }
  __syncthreads();
}

struct ProjSh {
  float xs[16][68];
  float ws[64][20];
  float ysh[16][17];
  float xps[16][16];
  float pr[16][4];
};

// ======================= fused persistent kernel ===========================
// 6 phases, 5 custom grid barriers. Regular (capturable) launch; grid sized
// from the occupancy API so all blocks are co-resident.
__global__ __launch_bounds__(256) void k_mega2(
    const float* __restrict__ x, const float* __restrict__ proj_w,
    const float* __restrict__ proj_b, const float* __restrict__ ln1_g,
    const float* __restrict__ ln1_b, const float* __restrict__ pi_w1,
    const float* __restrict__ pi_b1, const float* __restrict__ pi_w2,
    const float* __restrict__ pi_b2, const float* __restrict__ dtp,
    const float* __restrict__ fw, const float* __restrict__ fb,
    const float* __restrict__ ln2_g, const float* __restrict__ ln2_b,
    unsigned short* __restrict__ Kb, unsigned short* __restrict__ xvbT,
    unsigned short* __restrict__ fwTb, unsigned short* __restrict__ Z,
    float* __restrict__ xp, float* __restrict__ s, float* __restrict__ pi,
    float* __restrict__ v, float* __restrict__ dv, float* __restrict__ out,
    int* __restrict__ bar, int N, int D) {
  __shared__ __align__(16) unsigned char pool[32768];  // GEMM As+Bs = 32KB
  __shared__ float qs[4][4];
  const int tid = threadIdx.x;
  const int bid = blockIdx.x;
  const int nBlk = gridDim.x;
  const int lane = tid & 63, wv = tid >> 6;

  // ========= P0: proj -> LN1 -> ReLU (xp,s) + pi head + f_w transpose =====
  {
    int nProj = N / 16;
    int cols = D / 64;
    int nItems = nProj + cols * cols;
    for (int item = bid; item < nItems; item += nBlk) {
      __syncthreads();
      if (item >= nProj) {  // 64x64 transpose tile: fwTb[c][r] = bf16(fw[r][c])
        int t = item - nProj;
        unsigned short(*tile)[65] = (unsigned short(*)[65])pool;
        int c0 = (t % cols) * 64, r0 = (t / cols) * 64;
#pragma unroll
        for (int i = 0; i < 16; ++i) {
          int rr = wv * 16 + i;
          tile[rr][lane] = f2bf(fw[(size_t)(r0 + rr) * D + c0 + lane]);
        }
        __syncthreads();
#pragma unroll
        for (int i = 0; i < 16; ++i) {
          int rr = wv * 16 + i;
          fwTb[(size_t)(c0 + rr) * D + r0 + lane] = tile[lane][rr];
        }
        continue;
      }
      ProjSh& P = *(ProjSh*)pool;
      int row0 = item * 16;
      int row = tid >> 4, l = tid & 15;
      int skc = (tid & 15) * 4;
      int wk = tid >> 2, wl = (tid & 3) * 4;
      float acc = 0.f;
      for (int k0 = 0; k0 < D; k0 += 64) {
        float4 xv = *(const float4*)(x + (size_t)(row0 + row) * D + k0 + skc);
        float4 wvec = *(const float4*)(proj_w + (size_t)(k0 + wk) * 16 + wl);
        __syncthreads();
        *(float4*)&P.xs[row][skc] = xv;
        *(float4*)&P.ws[wk][wl] = wvec;
        __syncthreads();
#pragma unroll
        for (int kk = 0; kk < 64; kk += 4) {
          float4 a4 = *(const float4*)&P.xs[row][kk];
          acc += a4.x * P.ws[kk + 0][l];
          acc += a4.y * P.ws[kk + 1][l];
          acc += a4.z * P.ws[kk + 2][l];
          acc += a4.w * P.ws[kk + 3][l];
        }
      }
      float y = acc + proj_b[l];
      P.ysh[row][l] = y;
      __syncthreads();
      float mu = 0.f;
#pragma unroll
      for (int t = 0; t < 16; ++t) mu += P.ysh[row][t];
      mu *= (1.f / 16.f);
      float var = 0.f;
#pragma unroll
      for (int t = 0; t < 16; ++t) {
        float d2 = P.ysh[row][t] - mu;
        var += d2 * d2;
      }
      var *= (1.f / 16.f);
      float rstd = rsqrtf(var + LN_EPS);
      float xpv = fmaxf((y - mu) * rstd * ln1_g[l] + ln1_b[l], 0.f);
      P.xps[row][l] = xpv;
      xp[(size_t)(row0 + row) * 16 + l] = xpv;
      float sq = xpv * xpv;
      sq += __shfl_xor(sq, 8, 64);
      sq += __shfl_xor(sq, 4, 64);
      sq += __shfl_xor(sq, 2, 64);
      sq += __shfl_xor(sq, 1, 64);
      if ((lane & 15) == 0) s[row0 + row] = sq;
      __syncthreads();
      float w1r[3][16], b1r[3], w2r[3];  // D == 768
#pragma unroll
      for (int c = 0; c < 3; ++c) {
        int d0 = tid + c * 256;
        b1r[c] = pi_b1[d0];
        w2r[c] = pi_w2[d0];
#pragma unroll
        for (int t = 0; t < 16; ++t) w1r[c][t] = pi_w1[(size_t)t * D + d0];
      }
#pragma unroll
      for (int r = 0; r < 16; ++r) {
        float xv2[16];
#pragma unroll
        for (int t4 = 0; t4 < 4; ++t4) {
          float4 xq = *(const float4*)&P.xps[r][t4 * 4];
          xv2[t4 * 4 + 0] = xq.x;
          xv2[t4 * 4 + 1] = xq.y;
          xv2[t4 * 4 + 2] = xq.z;
          xv2[t4 * 4 + 3] = xq.w;
        }
        float pa = 0.f;
#pragma unroll
        for (int c = 0; c < 3; ++c) {
          float h = b1r[c];
#pragma unroll
          for (int t = 0; t < 16; ++t) h += xv2[t] * w1r[c][t];
          h = fmaxf(h, 0.f);
          pa += h * w2r[c];
        }
        float pv = wave_reduce(pa);
        if (lane == 0) P.pr[r][wv] = pv;
      }
      __syncthreads();
      if (tid < 16) {
        float tot = P.pr[tid][0] + P.pr[tid][1] + P.pr[tid][2] + P.pr[tid][3] +
                    pi_b2[0];
        pi[row0 + tid] = 1.f / (1.f + expf(-tot));
      }
    }
  }
  gridbar(bar + 0 * 256, nBlk, bid);

  // ========= P1: K_eps rows (bf16) + rowsum -> v ==========================
  {
    int nItems = N / 4;
    for (int item = bid; item < nItems; item += nBlk) {
      __syncthreads();
      int i0 = item * 4;
      float a[4][16], si[4];
#pragma unroll
      for (int r = 0; r < 4; ++r) {
        const float* ap = xp + (size_t)(i0 + r) * 16;
#pragma unroll
        for (int t = 0; t < 16; ++t) a[r][t] = ap[t];
        si[r] = s[i0 + r];
      }
      const float cc = 1.f / (4.f * EPSILON);
      float qa[4] = {0.f, 0.f, 0.f, 0.f};
      for (int it = 0; it < N / 512; ++it) {
        int j = it * 512 + tid * 2;
        const float4* bp = (const float4*)(xp + (size_t)j * 16);
        float4 b0 = bp[0], b1 = bp[1], b2 = bp[2], b3 = bp[3];
        float4 c0 = bp[4], c1 = bp[5], c2 = bp[6], c3 = bp[7];
        float bvv[16] = {b0.x, b0.y, b0.z, b0.w, b1.x, b1.y, b1.z, b1.w,
                         b2.x, b2.y, b2.z, b2.w, b3.x, b3.y, b3.z, b3.w};
        float cvv[16] = {c0.x, c0.y, c0.z, c0.w, c1.x, c1.y, c1.z, c1.w,
                         c2.x, c2.y, c2.z, c2.w, c3.x, c3.y, c3.z, c3.w};
        float sj0 = s[j], sj1 = s[j + 1];
#pragma unroll
        for (int r = 0; r < 4; ++r) {
          float d0 = 0.f, d1 = 0.f;
#pragma unroll
          for (int t = 0; t < 16; ++t) {
            d0 += a[r][t] * bvv[t];
            d1 += a[r][t] * cvv[t];
          }
          float k0 = __expf(-cc * (si[r] + sj0 - 2.f * d0));
          float k1 = __expf(-cc * (si[r] + sj1 - 2.f * d1));
          *(unsigned int*)(Kb + (size_t)(i0 + r) * N + j) = pack2(k0, k1);
          qa[r] += k0 + k1;
        }
      }
#pragma unroll
      for (int r = 0; r < 4; ++r) {
        float t = wave_reduce(qa[r]);
        if (lane == 0) qs[r][wv] = t;
      }
      __syncthreads();
      if (tid < 4) {
        float tot = qs[tid][0] + qs[tid][1] + qs[tid][2] + qs[tid][3];
        v[i0 + tid] = pi[i0 + tid] / tot;
      }
    }
  }
  gridbar(bar + 1 * 256, nBlk, bid);

  // ========= P2: dv (wave-per-row) + xvbT transpose tiles =================
  {
    int nDv = N / 4;
    int cols = D / 64;
    int nXT = cols * (N / 64);
    for (int item = bid; item < nDv + nXT; item += nBlk) {
      if (item < nDv) {
        int i = item * 4 + wv;
        const unsigned short* kr = Kb + (size_t)i * N;
        float acc = 0.f;
        for (int c0 = lane * 8; c0 < N; c0 += 512) {
          uint4 kv = *(const uint4*)(kr + c0);
          float4 va = *(const float4*)(v + c0);
          float4 vb = *(const float4*)(v + c0 + 4);
          unsigned int u;
          u = kv.x;
          acc += __uint_as_float(u << 16) * va.x +
                 __uint_as_float(u & 0xffff0000u) * va.y;
          u = kv.y;
          acc += __uint_as_float(u << 16) * va.z +
                 __uint_as_float(u & 0xffff0000u) * va.w;
          u = kv.z;
          acc += __uint_as_float(u << 16) * vb.x +
                 __uint_as_float(u & 0xffff0000u) * vb.y;
          u = kv.w;
          acc += __uint_as_float(u << 16) * vb.z +
                 __uint_as_float(u & 0xffff0000u) * vb.w;
        }
        acc = wave_reduce(acc);
        if (lane == 0) dv[i] = acc + 1e-5f;
      } else {  // 64x64: xvbT[d][j] = bf16(v[j]*x[j][d])
        int t = item - nDv;
        __syncthreads();
        unsigned short(*tile)[65] = (unsigned short(*)[65])pool;
        int c0 = (t % cols) * 64, r0 = (t / cols) * 64;
#pragma unroll
        for (int i = 0; i < 16; ++i) {
          int rr = wv * 16 + i;
          tile[rr][lane] =
              f2bf(v[r0 + rr] * x[(size_t)(r0 + rr) * D + c0 + lane]);
        }
        __syncthreads();
#pragma unroll
        for (int i = 0; i < 16; ++i) {
          int rr = wv * 16 + i;
          xvbT[(size_t)(c0 + rr) * N + r0 + lane] = tile[lane][rr];
        }
      }
    }
  }
  gridbar(bar + 2 * 256, nBlk, bid);

  // ========= P3: Y = Kb @ xvbT^T; Z = bf16(c2*x + (c3b/dv)*Y) =============
  {
    float dtv = dtp[0];
    float c2 = (1.f - ALPHA) * (1.f - 2.f * dtv);
    float c3b = (1.f - ALPHA) * 2.f * dtv / EPSILON;
    unsigned short* As = (unsigned short*)pool;
    unsigned short* Bs = As + 64 * 128;
    int tilesX = D / 64;
    int nT = tilesX * (N / 64);
    int ln = lane & 15, quad = lane >> 4;
    int mh = (wv & 1) * 32, nh = (wv >> 1) * 32;
    int srow = wv * 4 + quad;
    int swz = (ln ^ srow) * 8;
    for (int item = bid; item < nT; item += nBlk) {
      int row0 = (item / tilesX) * 64, col0 = (item % tilesX) * 64;
      const unsigned short* gA = Kb + (size_t)(row0 + srow) * N + swz;
      const unsigned short* gB = xvbT + (size_t)(col0 + srow) * N + swz;
      f32x4 acc[2][2] = {};
      for (int k0 = 0; k0 < N; k0 += 128) {
        __syncthreads();
#pragma unroll
        for (int q = 0; q < 4; ++q) {
          async16(gA + (size_t)q * 16 * N + k0, As + (q * 16 + wv * 4) * 128);
          async16(gB + (size_t)q * 16 * N + k0, Bs + (q * 16 + wv * 4) * 128);
        }
        __syncthreads();
#pragma unroll
        for (int ks = 0; ks < 4; ++ks) {
          bf16x8 bfr[2], afr[2];
#pragma unroll
          for (int nt = 0; nt < 2; ++nt) {
            int r = nh + nt * 16 + ln;
            int cix = (ks * 4 + quad) ^ (r & 15);
            bfr[nt] = *(const bf16x8*)&Bs[r * 128 + cix * 8];
          }
#pragma unroll
          for (int mt = 0; mt < 2; ++mt) {
            int r = mh + mt * 16 + ln;
            int cix = (ks * 4 + quad) ^ (r & 15);
            afr[mt] = *(const bf16x8*)&As[r * 128 + cix * 8];
          }
#pragma unroll
          for (int mt = 0; mt < 2; ++mt)
#pragma unroll
            for (int nt = 0; nt < 2; ++nt)
              acc[mt][nt] = __builtin_amdgcn_mfma_f32_16x16x32_bf16(
                  afr[mt], bfr[nt], acc[mt][nt], 0, 0, 0);
        }
      }
#pragma unroll
      for (int mt = 0; mt < 2; ++mt)
#pragma unroll
        for (int nt = 0; nt < 2; ++nt) {
          int col = col0 + nh + nt * 16 + ln;
#pragma unroll
          for (int r = 0; r < 4; ++r) {
            int row = row0 + mh + mt * 16 + quad * 4 + r;
            float c3 = c3b / dv[row];
            Z[(size_t)row * D + col] =
                f2bf(c2 * x[(size_t)row * D + col] + c3 * acc[mt][nt][r]);
          }
        }
    }
  }
  gridbar(bar + 3 * 256, nBlk, bid);

  // ========= P4: pre = ALPHA*x + Z @ fwTb^T + cb*fb ======================
  {
    float dtv = dtp[0];
    float cb = (1.f - ALPHA) * (1.f - 2.f * dtv) +
               (1.f - ALPHA) * 2.f * dtv / EPSILON;
    unsigned short* As = (unsigned short*)pool;
    unsigned short* Bs = As + 64 * 128;
    int tilesX = D / 64;
    int nT = tilesX * (N / 64);
    int ln = lane & 15, quad = lane >> 4;
    int mh = (wv & 1) * 32, nh = (wv >> 1) * 32;
    int srow = wv * 4 + quad;
    int swz = (ln ^ srow) * 8;
    for (int item = bid; item < nT; item += nBlk) {
      int row0 = (item / tilesX) * 64, col0 = (item % tilesX) * 64;
      const unsigned short* gA = Z + (size_t)(row0 + srow) * D + swz;
      const unsigned short* gB = fwTb + (size_t)(col0 + srow) * D + swz;
      f32x4 acc[2][2] = {};
      for (int k0 = 0; k0 < D; k0 += 128) {
        __syncthreads();
#pragma unroll
        for (int q = 0; q < 4; ++q) {
          async16(gA + (size_t)q * 16 * D + k0, As + (q * 16 + wv * 4) * 128);
          async16(gB + (size_t)q * 16 * D + k0, Bs + (q * 16 + wv * 4) * 128);
        }
        __syncthreads();
#pragma unroll
        for (int ks = 0; ks < 4; ++ks) {
          bf16x8 bfr[2], afr[2];
#pragma unroll
          for (int nt = 0; nt < 2; ++nt) {
            int r = nh + nt * 16 + ln;
            int cix = (ks * 4 + quad) ^ (r & 15);
            bfr[nt] = *(const bf16x8*)&Bs[r * 128 + cix * 8];
          }
#pragma unroll
          for (int mt = 0; mt < 2; ++mt) {
            int r = mh + mt * 16 + ln;
            int cix = (ks * 4 + quad) ^ (r & 15);
            afr[mt] = *(const bf16x8*)&As[r * 128 + cix * 8];
          }
#pragma unroll
          for (int mt = 0; mt < 2; ++mt)
#pragma unroll
            for (int nt = 0; nt < 2; ++nt)
              acc[mt][nt] = __builtin_amdgcn_mfma_f32_16x16x32_bf16(
                  afr[mt], bfr[nt], acc[mt][nt], 0, 0, 0);
        }
      }
#pragma unroll
      for (int mt = 0; mt < 2; ++mt)
#pragma unroll
        for (int nt = 0; nt < 2; ++nt) {
          int col = col0 + nh + nt * 16 + ln;
          float bv = cb * fb[col];
#pragma unroll
          for (int r = 0; r < 4; ++r) {
            int row = row0 + mh + mt * 16 + quad * 4 + r;
            size_t idx = (size_t)row * D + col;
            out[idx] = ALPHA * x[idx] + acc[mt][nt][r] + bv;
          }
        }
    }
  }
  gridbar(bar + 4 * 256, nBlk, bid);

  // ========= P5: in-place row LayerNorm (1 wave / row) ====================
  {
    int nItems = N / 4;
    for (int item = bid; item < nItems; item += nBlk) {
      int i = item * 4 + wv;
      float4 vv[3];  // D == 768
      float sum = 0.f;
#pragma unroll
      for (int t = 0; t < 3; ++t) {
        vv[t] = *(const float4*)(out + (size_t)i * D + lane * 4 + t * 256);
        sum += vv[t].x + vv[t].y + vv[t].z + vv[t].w;
      }
      float mu = wave_reduce(sum) / (float)D;
      float sq = 0.f;
#pragma unroll
      for (int t = 0; t < 3; ++t) {
        float dx = vv[t].x - mu, dy = vv[t].y - mu;
        float dz = vv[t].z - mu, dw = vv[t].w - mu;
        sq += dx * dx + dy * dy + dz * dz + dw * dw;
      }
      float var = wave_reduce(sq) / (float)D;
      float rs = rsqrtf(var + LN_EPS);
#pragma unroll
      for (int t = 0; t < 3; ++t) {
        int d0 = lane * 4 + t * 256;
        float4 gv = *(const float4*)(ln2_g + d0);
        float4 bv = *(const float4*)(ln2_b + d0);
        float4 o;
        o.x = (vv[t].x - mu) * rs * gv.x + bv.x;
        o.y = (vv[t].y - mu) * rs * gv.y + bv.y;
        o.z = (vv[t].z - mu) * rs * gv.z + bv.z;
        o.w = (vv[t].w - mu) * rs * gv.w + bv.w;
        *(float4*)(out + (size_t)i * D + d0) = o;
      }
    }
  }
}

// ===================== legacy 6-kernel fallback path =======================

__global__ __launch_bounds__(256) void k_proj(
    const float* __restrict__ x, const float* __restrict__ proj_w,
    const float* __restrict__ proj_b, const float* __restrict__ ln1_g,
    const float* __restrict__ ln1_b, const float* __restrict__ pi_w1,
    const float* __restrict__ pi_b1, const float* __restrict__ pi_w2,
    const float* __restrict__ pi_b2, const float* __restrict__ fw,
    unsigned short* __restrict__ fwTb, float* __restrict__ xp,
    float* __restrict__ s, float* __restrict__ pi, int N, int D) {
  __shared__ float xs[16][68];
  __shared__ float ws[64][20];
  __shared__ float ysh[16][17];
  __shared__ float xps[16][16];
  __shared__ float pr[16][4];
  int tid = threadIdx.x;
  int nProj = N / 16;
  if (blockIdx.x >= (unsigned)nProj) {
    unsigned short(*tile)[33] = (unsigned short(*)[33])&ws[0][0];
    int t = blockIdx.x - nProj;
    int tx = tid & 31, ty = tid >> 5;
    int cols = D / 32;
    int c0 = (t % cols) * 32, r0 = (t / cols) * 32;
#pragma unroll
    for (int i = 0; i < 4; ++i) {
      int r = r0 + ty + i * 8;
      tile[ty + i * 8][tx] = f2bf(fw[(size_t)r * D + c0 + tx]);
    }
    __syncthreads();
#pragma unroll
    for (int i = 0; i < 4; ++i) {
      int cc = c0 + ty + i * 8;
      fwTb[(size_t)cc * D + r0 + tx] = tile[tx][ty + i * 8];
    }
    return;
  }
  int row0 = blockIdx.x * 16;
  int row = tid >> 4, l = tid & 15;
  int lane = tid & 63, w = tid >> 6;
  int skc = (tid & 15) * 4;
  int wk = tid >> 2, wl = (tid & 3) * 4;
  float acc = 0.f;
  for (int k0 = 0; k0 < D; k0 += 64) {
    float4 xv = *(const float4*)(x + (size_t)(row0 + row) * D + k0 + skc);
    float4 wv = *(const float4*)(proj_w + (size_t)(k0 + wk) * 16 + wl);
    __syncthreads();
    *(float4*)&xs[row][skc] = xv;
    *(float4*)&ws[wk][wl] = wv;
    __syncthreads();
#pragma unroll
    for (int kk = 0; kk < 64; kk += 4) {
      float4 a4 = *(const float4*)&xs[row][kk];
      acc += a4.x * ws[kk + 0][l];
      acc += a4.y * ws[kk + 1][l];
      acc += a4.z * ws[kk + 2][l];
      acc += a4.w * ws[kk + 3][l];
    }
  }
  float y = acc + proj_b[l];
  ysh[row][l] = y;
  __syncthreads();
  float mu = 0.f;
#pragma unroll
  for (int t = 0; t < 16; ++t) mu += ysh[row][t];
  mu *= (1.f / 16.f);
  float var = 0.f;
#pragma unroll
  for (int t = 0; t < 16; ++t) { float d2 = ysh[row][t] - mu; var += d2 * d2; }
  var *= (1.f / 16.f);
  float rstd = rsqrtf(var + LN_EPS);
  float xpv = fmaxf((y - mu) * rstd * ln1_g[l] + ln1_b[l], 0.f);
  xps[row][l] = xpv;
  xp[(size_t)(row0 + row) * 16 + l] = xpv;
  float sq = xpv * xpv;
  sq += __shfl_xor(sq, 8, 64);
  sq += __shfl_xor(sq, 4, 64);
  sq += __shfl_xor(sq, 2, 64);
  sq += __shfl_xor(sq, 1, 64);
  if ((lane & 15) == 0) s[row0 + row] = sq;
  __syncthreads();
  float w1r[3][16], b1r[3], w2r[3];
#pragma unroll
  for (int c = 0; c < 3; ++c) {
    int d0 = tid + c * 256;
    b1r[c] = pi_b1[d0];
    w2r[c] = pi_w2[d0];
#pragma unroll
    for (int t = 0; t < 16; ++t) w1r[c][t] = pi_w1[(size_t)t * D + d0];
  }
#pragma unroll
  for (int r = 0; r < 16; ++r) {
    float xv[16];
#pragma unroll
    for (int t4 = 0; t4 < 4; ++t4) {
      float4 xq = *(const float4*)&xps[r][t4 * 4];
      xv[t4 * 4 + 0] = xq.x; xv[t4 * 4 + 1] = xq.y;
      xv[t4 * 4 + 2] = xq.z; xv[t4 * 4 + 3] = xq.w;
    }
    float pa = 0.f;
#pragma unroll
    for (int c = 0; c < 3; ++c) {
      float h = b1r[c];
#pragma unroll
      for (int t = 0; t < 16; ++t) h += xv[t] * w1r[c][t];
      h = fmaxf(h, 0.f);
      pa += h * w2r[c];
    }
    float pv = wave_reduce(pa);
    if (lane == 0) pr[r][w] = pv;
  }
  __syncthreads();
  if (tid < 16) {
    float tot = pr[tid][0] + pr[tid][1] + pr[tid][2] + pr[tid][3] + pi_b2[0];
    pi[row0 + tid] = 1.f / (1.f + expf(-tot));
  }
}

__global__ __launch_bounds__(256) void k_keps(
    const float* __restrict__ xp, const float* __restrict__ s,
    const float* __restrict__ pi, unsigned short* __restrict__ Kb,
    float* __restrict__ v, int N) {
  __shared__ float qs[4][4];
  int i0 = blockIdx.x * 4;
  int tid = threadIdx.x, lane = tid & 63, w = tid >> 6;
  float a[4][16], si[4];
#pragma unroll
  for (int r = 0; r < 4; ++r) {
    const float* ap = xp + (size_t)(i0 + r) * 16;
#pragma unroll
    for (int t = 0; t < 16; ++t) a[r][t] = ap[t];
    si[r] = s[i0 + r];
  }
  const float c = 1.f / (4.f * EPSILON);
  float qa[4] = {0.f, 0.f, 0.f, 0.f};
  for (int it = 0; it < N / 512; ++it) {
    int j = it * 512 + tid * 2;
    const float4* bp = (const float4*)(xp + (size_t)j * 16);
    float4 b0 = bp[0], b1 = bp[1], b2 = bp[2], b3 = bp[3];
    float4 c0 = bp[4], c1 = bp[5], c2 = bp[6], c3 = bp[7];
    float bv[16] = {b0.x, b0.y, b0.z, b0.w, b1.x, b1.y, b1.z, b1.w,
                    b2.x, b2.y, b2.z, b2.w, b3.x, b3.y, b3.z, b3.w};
    float cv[16] = {c0.x, c0.y, c0.z, c0.w, c1.x, c1.y, c1.z, c1.w,
                    c2.x, c2.y, c2.z, c2.w, c3.x, c3.y, c3.z, c3.w};
    float sj0 = s[j], sj1 = s[j + 1];
#pragma unroll
    for (int r = 0; r < 4; ++r) {
      float d0 = 0.f, d1 = 0.f;
#pragma unroll
      for (int t = 0; t < 16; ++t) { d0 += a[r][t] * bv[t]; d1 += a[r][t] * cv[t]; }
      float k0 = __expf(-c * (si[r] + sj0 - 2.f * d0));
      float k1 = __expf(-c * (si[r] + sj1 - 2.f * d1));
      *(unsigned int*)(Kb + (size_t)(i0 + r) * N + j) = pack2(k0, k1);
      qa[r] += k0 + k1;
    }
  }
#pragma unroll
  for (int r = 0; r < 4; ++r) {
    float t = wave_reduce(qa[r]);
    if (lane == 0) qs[r][w] = t;
  }
  __syncthreads();
  if (tid < 4) {
    float tot = qs[tid][0] + qs[tid][1] + qs[tid][2] + qs[tid][3];
    v[i0 + tid] = pi[i0 + tid] / tot;
  }
}

__global__ __launch_bounds__(256) void k_prep(
    const unsigned short* __restrict__ Kb, const float* __restrict__ v,
    float* __restrict__ dv, const float* __restrict__ x,
    unsigned short* __restrict__ xvbT, int N, int D) {
  __shared__ float sh[544];
  int bid = blockIdx.x, tid = threadIdx.x;
  if (bid < N) {
    int i = bid;
    float acc = 0.f;
    for (int j8 = tid * 8; j8 < N; j8 += 256 * 8) {
      uint4 kv4 = *(const uint4*)(Kb + (size_t)i * N + j8);
      float4 va = *(const float4*)(v + j8);
      float4 vb = *(const float4*)(v + j8 + 4);
      unsigned int u;
      u = kv4.x;
      acc += __uint_as_float(u << 16) * va.x + __uint_as_float(u & 0xffff0000u) * va.y;
      u = kv4.y;
      acc += __uint_as_float(u << 16) * va.z + __uint_as_float(u & 0xffff0000u) * va.w;
      u = kv4.z;
      acc += __uint_as_float(u << 16) * vb.x + __uint_as_float(u & 0xffff0000u) * vb.y;
      u = kv4.w;
      acc += __uint_as_float(u << 16) * vb.z + __uint_as_float(u & 0xffff0000u) * vb.w;
    }
    float tot = blk_reduce_sum(acc, sh);
    if (tid == 0) dv[i] = tot + 1e-5f;
  } else {
    int t = bid - N;
    unsigned short(*tile)[33] = (unsigned short(*)[33])sh;
    int tx = tid & 31, ty = tid >> 5;
    int cols = D / 32;
    int c0 = (t % cols) * 32;
    int r0 = (t / cols) * 32;
#pragma unroll
    for (int i = 0; i < 4; ++i) {
      int r = r0 + ty + i * 8;
      tile[ty + i * 8][tx] = f2bf(v[r] * x[(size_t)r * D + c0 + tx]);
    }
    __syncthreads();
#pragma unroll
    for (int i = 0; i < 4; ++i) {
      int cc = c0 + ty + i * 8;
      xvbT[(size_t)cc * N + r0 + tx] = tile[tx][ty + i * 8];
    }
  }
}

#define GEMM_KLOOP(Aptr, Bptr, Kdim)                                          \
  int tid = threadIdx.x;                                                      \
  int w = tid >> 6, l = tid & 63;                                             \
  int ln = l & 15, quad = l >> 4;                                             \
  int mh = (w & 1) * 32, nh = (w >> 1) * 32;                                  \
  int row0 = blockIdx.y * 64, col0 = blockIdx.x * 64;                         \
  int srow = w * 4 + (l >> 4);                                                \
  int swz = ((l & 15) ^ srow) * 8;                                            \
  const unsigned short* gA = Aptr + (size_t)(row0 + srow) * Kdim + swz;       \
  const unsigned short* gB = Bptr + (size_t)(col0 + srow) * Kdim + swz;       \
  f32x4 acc[2][2] = {};                                                       \
  for (int k0 = 0; k0 < Kdim; k0 += 128) {                                    \
    __syncthreads();                                                          \
    _Pragma("unroll")                                                         \
    for (int q = 0; q < 4; ++q) {                                             \
      async16(gA + (size_t)q * 16 * Kdim + k0, As + (q * 16 + w * 4) * 128);  \
      async16(gB + (size_t)q * 16 * Kdim + k0, Bs + (q * 16 + w * 4) * 128);  \
    }                                                                         \
    __syncthreads();                                                          \
    _Pragma("unroll")                                                         \
    for (int ks = 0; ks < 4; ++ks) {                                          \
      bf16x8 bfr[2], afr[2];                                                  \
      _Pragma("unroll")                                                       \
      for (int nt = 0; nt < 2; ++nt) {                                        \
        int r = nh + nt * 16 + ln;                                            \
        int cix = (ks * 4 + quad) ^ (r & 15);                                 \
        bfr[nt] = *(const bf16x8*)&Bs[r * 128 + cix * 8];                     \
      }                                                                       \
      _Pragma("unroll")                                                       \
      for (int mt = 0; mt < 2; ++mt) {                                        \
        int r = mh + mt * 16 + ln;                                            \
        int cix = (ks * 4 + quad) ^ (r & 15);                                 \
        afr[mt] = *(const bf16x8*)&As[r * 128 + cix * 8];                     \
      }                                                                       \
      _Pragma("unroll")                                                       \
      for (int mt = 0; mt < 2; ++mt)                                          \
        _Pragma("unroll")                                                     \
        for (int nt = 0; nt < 2; ++nt)                                        \
          acc[mt][nt] = __builtin_amdgcn_mfma_f32_16x16x32_bf16(              \
              afr[mt], bfr[nt], acc[mt][nt], 0, 0, 0);                        \
    }                                                                         \
  }

__global__ __launch_bounds__(256) void k_gemmA(
    const unsigned short* __restrict__ A, const unsigned short* __restrict__ Bt,
    const float* __restrict__ x, const float* __restrict__ dv,
    const float* __restrict__ dtp, unsigned short* __restrict__ Z,
    int M, int N, int K) {
  __shared__ unsigned short As[64 * 128];
  __shared__ unsigned short Bs[64 * 128];
  GEMM_KLOOP(A, Bt, K)
  float dtv = dtp[0];
  float c2 = (1.f - ALPHA) * (1.f - 2.f * dtv);
  float c3b = (1.f - ALPHA) * 2.f * dtv / EPSILON;
#pragma unroll
  for (int mt = 0; mt < 2; ++mt)
#pragma unroll
    for (int nt = 0; nt < 2; ++nt) {
      int col = col0 + nh + nt * 16 + ln;
#pragma unroll
      for (int r = 0; r < 4; ++r) {
        int row = row0 + mh + mt * 16 + quad * 4 + r;
        float c3 = c3b / dv[row];
        Z[(size_t)row * N + col] =
            f2bf(c2 * x[(size_t)row * N + col] + c3 * acc[mt][nt][r]);
      }
    }
}

__global__ __launch_bounds__(256) void k_gemmB(
    const unsigned short* __restrict__ A, const unsigned short* __restrict__ Bt,
    const float* __restrict__ x, const float* __restrict__ bias,
    const float* __restrict__ dtp, float* __restrict__ out,
    int M, int N, int K) {
  __shared__ unsigned short As[64 * 128];
  __shared__ unsigned short Bs[64 * 128];
  GEMM_KLOOP(A, Bt, K)
  float dtv = dtp[0];
  float cb = (1.f - ALPHA) * (1.f - 2.f * dtv) +
             (1.f - ALPHA) * 2.f * dtv / EPSILON;
#pragma unroll
  for (int mt = 0; mt < 2; ++mt)
#pragma unroll
    for (int nt = 0; nt < 2; ++nt) {
      int col = col0 + nh + nt * 16 + ln;
      float bv = cb * bias[col];
#pragma unroll
      for (int r = 0; r < 4; ++r) {
        int row = row0 + mh + mt * 16 + quad * 4 + r;
        size_t idx = (size_t)row * N + col;
        out[idx] = ALPHA * x[idx] + acc[mt][nt][r] + bv;
      }
    }
}

__global__ __launch_bounds__(256) void k_ln_rows(
    float* __restrict__ out, const float* __restrict__ g,
    const float* __restrict__ b, int D) {
  __shared__ float red[4];
  int i = blockIdx.x, tid = threadIdx.x;
  float vv[4];
  int nt = D / 256;
  float sum = 0.f;
  for (int t = 0; t < nt; ++t) {
    vv[t] = out[(size_t)i * D + tid + t * 256];
    sum += vv[t];
  }
  float mu = blk_reduce_sum(sum, red) / (float)D;
  float sq = 0.f;
  for (int t = 0; t < nt; ++t) { float d2 = vv[t] - mu; sq += d2 * d2; }
  float var = blk_reduce_sum(sq, red) / (float)D;
  float rs = rsqrtf(var + LN_EPS);
  for (int t = 0; t < nt; ++t) {
    int d0 = tid + t * 256;
    out[(size_t)i * D + d0] = (vv[t] - mu) * rs * g[d0] + b[d0];
  }
}

extern "C" void kernel_launch(void* const* d_in, const int* in_sizes, int n_in,
                              void* d_out, int out_size, void* d_ws, size_t ws_size,
                              hipStream_t stream) {
  const float* x = (const float*)d_in[0];
  const float* proj_w = (const float*)d_in[1];
  const float* proj_b = (const float*)d_in[2];
  const float* ln1_g = (const float*)d_in[3];
  const float* ln1_b = (const float*)d_in[4];
  const float* pi_w1 = (const float*)d_in[5];
  const float* pi_b1 = (const float*)d_in[6];
  const float* pi_w2 = (const float*)d_in[7];
  const float* pi_b2 = (const float*)d_in[8];
  const float* dt = (const float*)d_in[9];
  const float* f_w = (const float*)d_in[10];
  const float* f_b = (const float*)d_in[11];
  const float* ln2_g = (const float*)d_in[12];
  const float* ln2_b = (const float*)d_in[13];
  float* out = (float*)d_out;

  int D = in_sizes[11];      // 768
  int N = in_sizes[0] / D;   // 2048

  unsigned short* Kb = (unsigned short*)d_ws;                   // N*N bf16
  unsigned short* xvbT = Kb + (size_t)N * N;                    // D*N bf16
  unsigned short* fwTb = xvbT + (size_t)D * N;                  // D*D bf16
  unsigned short* Z = fwTb + (size_t)D * D;                     // N*D bf16
  float* xp = (float*)(Z + (size_t)N * D);                      // N*16
  float* s = xp + (size_t)N * 16;                               // N
  float* pi = s + N;                                            // N
  float* v = pi + N;                                            // N
  float* dv = v + N;                                            // N
  // barrier counters: aligned past the float scratch.
  // 5 barriers x 8 lines x 32 ints = 1280 ints (5 KB)
  char* dvEnd = (char*)(dv + N);
  int* bar = (int*)((((uintptr_t)dvEnd) + 255) & ~(uintptr_t)255);

  // ---- preferred path: persistent kernel + custom grid barriers ----
  bool ok = false;
  int maxBlk = 0;
  hipError_t qerr =
      hipOccupancyMaxActiveBlocksPerMultiprocessor(&maxBlk, k_mega2, 256, 0);
  if (qerr == hipSuccess && maxBlk > 0) {
    int dev = 0, numCU = 256;
    hipGetDevice(&dev);
    hipDeviceGetAttribute(&numCU, hipDeviceAttributeMultiprocessorCount, dev);
    long cap = (long)maxBlk * (long)numCU;
    int grid = (int)(cap < 512 ? cap : 512);
    if (grid >= 64) {
      hipMemsetAsync(bar, 0, 5 * 256 * sizeof(int), stream);
      k_mega2<<<grid, 256, 0, stream>>>(
          x, proj_w, proj_b, ln1_g, ln1_b, pi_w1, pi_b1, pi_w2, pi_b2, dt,
          f_w, f_b, ln2_g, ln2_b, Kb, xvbT, fwTb, Z, xp, s, pi, v, dv, out,
          bar, N, D);
      ok = true;
    }
  }

  if (!ok) {
    // ---- fallback: proven 6-kernel pipeline ----
    int fwB = (D / 32) * (D / 32);
    int xvtB = (D / 32) * (N / 32);
    k_proj<<<N / 16 + fwB, 256, 0, stream>>>(x, proj_w, proj_b, ln1_g, ln1_b,
                                             pi_w1, pi_b1, pi_w2, pi_b2, f_w,
                                             fwTb, xp, s, pi, N, D);
    k_keps<<<N / 4, 256, 0, stream>>>(xp, s, pi, Kb, v, N);
    k_prep<<<N + xvtB, 256, 0, stream>>>(Kb, v, dv, x, xvbT, N, D);
    k_gemmA<<<dim3(D / 64, N / 64), 256, 0, stream>>>(Kb, xvbT, x, dv, dt, Z,
                                                      N, D, N);
    k_gemmB<<<dim3(D / 64, N / 64), 256, 0, stream>>>(Z, fwTb, x, f_b, dt, out,
                                                      N, D, D);
    k_ln_rows<<<N, 256, 0, stream>>>(out, ln2_g, ln2_b, D);
  }
}

// Round 4
// 157.612 us; speedup vs baseline: 1.0064x; 1.0064x over previous
//
#include <hip/hip_runtime.h>
#include <math.h>

#define EPSILON 0.3f
#define ALPHA 0.7f
#define LN_EPS 1e-5f

typedef __bf16 bf16x8 __attribute__((ext_vector_type(8)));
typedef float f32x4 __attribute__((ext_vector_type(4)));

__device__ __forceinline__ unsigned short f2bf(float f) {
  unsigned int u = __float_as_uint(f);
  return (unsigned short)((u + 0x7fffu + ((u >> 16) & 1u)) >> 16);
}
__device__ __forceinline__ unsigned int pack2(float lo, float hi) {
  return (unsigned int)f2bf(lo) | ((unsigned int)f2bf(hi) << 16);
}

// async 16B/lane global->LDS DMA; lds base wave-uniform (HW adds lane*16)
__device__ __forceinline__ void async16(const unsigned short* g,
                                        unsigned short* l) {
  __builtin_amdgcn_global_load_lds(
      (const __attribute__((address_space(1))) unsigned int*)g,
      (__attribute__((address_space(3))) unsigned int*)l, 16, 0, 0);
}

__device__ __forceinline__ float wave_reduce(float v) {
#pragma unroll
  for (int off = 32; off > 0; off >>= 1) v += __shfl_xor(v, off, 64);
  return v;
}

__device__ __forceinline__ float blk_reduce_sum(float v, float* red) {
  v = wave_reduce(v);
  int lane = threadIdx.x & 63, wid = threadIdx.x >> 6;
  __syncthreads();
  if (lane == 0) red[wid] = v;
  __syncthreads();
  return red[0] + red[1] + red[2] + red[3];
}

// Grid barrier, RMW-free polling, arrival counters spread over 8 cachelines.
// Counters zeroed host-side (in-graph memsetAsync); each slot used once/run.
__device__ __forceinline__ void gridbar(int* base, int nBlk, int bid) {
  __syncthreads();
  if (threadIdx.x == 0) {
    __threadfence();  // release
    __hip_atomic_fetch_add(base + (bid & 7) * 32, 1, __ATOMIC_RELAXED,
                           __HIP_MEMORY_SCOPE_AGENT);
    int iters = 0;
    for (;;) {
      int sum = 0;
#pragma unroll
      for (int i = 0; i < 8; ++i)
        sum += __hip_atomic_load(base + i * 32, __ATOMIC_RELAXED,
                                 __HIP_MEMORY_SCOPE_AGENT);
      if (sum >= nBlk) break;
      __builtin_amdgcn_s_sleep(4);
      if (++iters > (1 << 20)) break;  // livelock failsafe
    }
    __threadfence();  // acquire
  }
  __syncthreads();
}

struct ProjSh {
  float xs[16][68];
  float ws[64][20];
  float ysh[16][17];
  float xps[16][16];
  float pr[16][4];
};

// ======================= fused persistent kernel ===========================
// 6 phases, 5 custom grid barriers. GEMM phases double-buffered (T3 2-phase)
// with XCD-chunked tile assignment (T1) for L2 locality.
__global__ __launch_bounds__(256) void k_mega2(
    const float* __restrict__ x, const float* __restrict__ proj_w,
    const float* __restrict__ proj_b, const float* __restrict__ ln1_g,
    const float* __restrict__ ln1_b, const float* __restrict__ pi_w1,
    const float* __restrict__ pi_b1, const float* __restrict__ pi_w2,
    const float* __restrict__ pi_b2, const float* __restrict__ dtp,
    const float* __restrict__ fw, const float* __restrict__ fb,
    const float* __restrict__ ln2_g, const float* __restrict__ ln2_b,
    unsigned short* __restrict__ Kb, unsigned short* __restrict__ xvbT,
    unsigned short* __restrict__ fwTb, unsigned short* __restrict__ Z,
    float* __restrict__ xp, float* __restrict__ s, float* __restrict__ pi,
    float* __restrict__ v, float* __restrict__ dv, float* __restrict__ out,
    int* __restrict__ bar, int N, int D) {
  // 64 KB: As0|Bs0|As1|Bs1, each 64x128 bf16 (16 KB)
  __shared__ __align__(16) unsigned char pool[65536];
  __shared__ float qs[4][4];
  const int tid = threadIdx.x;
  const int bid = blockIdx.x;
  const int nBlk = gridDim.x;
  const int lane = tid & 63, wv = tid >> 6;

  // ========= P0: proj -> LN1 -> ReLU (xp,s) + pi head + f_w transpose =====
  {
    int nProj = N / 16;
    int cols = D / 64;
    int nItems = nProj + cols * cols;
    for (int item = bid; item < nItems; item += nBlk) {
      __syncthreads();
      if (item >= nProj) {  // 64x64 transpose tile: fwTb[c][r] = bf16(fw[r][c])
        int t = item - nProj;
        unsigned short(*tile)[65] = (unsigned short(*)[65])pool;
        int c0 = (t % cols) * 64, r0 = (t / cols) * 64;
#pragma unroll
        for (int i = 0; i < 16; ++i) {
          int rr = wv * 16 + i;
          tile[rr][lane] = f2bf(fw[(size_t)(r0 + rr) * D + c0 + lane]);
        }
        __syncthreads();
#pragma unroll
        for (int i = 0; i < 16; ++i) {
          int rr = wv * 16 + i;
          fwTb[(size_t)(c0 + rr) * D + r0 + lane] = tile[lane][rr];
        }
        continue;
      }
      ProjSh& P = *(ProjSh*)pool;
      int row0 = item * 16;
      int row = tid >> 4, l = tid & 15;
      int skc = (tid & 15) * 4;
      int wk = tid >> 2, wl = (tid & 3) * 4;
      float acc = 0.f;
      for (int k0 = 0; k0 < D; k0 += 64) {
        float4 xv = *(const float4*)(x + (size_t)(row0 + row) * D + k0 + skc);
        float4 wvec = *(const float4*)(proj_w + (size_t)(k0 + wk) * 16 + wl);
        __syncthreads();
        *(float4*)&P.xs[row][skc] = xv;
        *(float4*)&P.ws[wk][wl] = wvec;
        __syncthreads();
#pragma unroll
        for (int kk = 0; kk < 64; kk += 4) {
          float4 a4 = *(const float4*)&P.xs[row][kk];
          acc += a4.x * P.ws[kk + 0][l];
          acc += a4.y * P.ws[kk + 1][l];
          acc += a4.z * P.ws[kk + 2][l];
          acc += a4.w * P.ws[kk + 3][l];
        }
      }
      float y = acc + proj_b[l];
      P.ysh[row][l] = y;
      __syncthreads();
      float mu = 0.f;
#pragma unroll
      for (int t = 0; t < 16; ++t) mu += P.ysh[row][t];
      mu *= (1.f / 16.f);
      float var = 0.f;
#pragma unroll
      for (int t = 0; t < 16; ++t) {
        float d2 = P.ysh[row][t] - mu;
        var += d2 * d2;
      }
      var *= (1.f / 16.f);
      float rstd = rsqrtf(var + LN_EPS);
      float xpv = fmaxf((y - mu) * rstd * ln1_g[l] + ln1_b[l], 0.f);
      P.xps[row][l] = xpv;
      xp[(size_t)(row0 + row) * 16 + l] = xpv;
      float sq = xpv * xpv;
      sq += __shfl_xor(sq, 8, 64);
      sq += __shfl_xor(sq, 4, 64);
      sq += __shfl_xor(sq, 2, 64);
      sq += __shfl_xor(sq, 1, 64);
      if ((lane & 15) == 0) s[row0 + row] = sq;
      __syncthreads();
      float w1r[3][16], b1r[3], w2r[3];  // D == 768
#pragma unroll
      for (int c = 0; c < 3; ++c) {
        int d0 = tid + c * 256;
        b1r[c] = pi_b1[d0];
        w2r[c] = pi_w2[d0];
#pragma unroll
        for (int t = 0; t < 16; ++t) w1r[c][t] = pi_w1[(size_t)t * D + d0];
      }
#pragma unroll
      for (int r = 0; r < 16; ++r) {
        float xv2[16];
#pragma unroll
        for (int t4 = 0; t4 < 4; ++t4) {
          float4 xq = *(const float4*)&P.xps[r][t4 * 4];
          xv2[t4 * 4 + 0] = xq.x;
          xv2[t4 * 4 + 1] = xq.y;
          xv2[t4 * 4 + 2] = xq.z;
          xv2[t4 * 4 + 3] = xq.w;
        }
        float pa = 0.f;
#pragma unroll
        for (int c = 0; c < 3; ++c) {
          float h = b1r[c];
#pragma unroll
          for (int t = 0; t < 16; ++t) h += xv2[t] * w1r[c][t];
          h = fmaxf(h, 0.f);
          pa += h * w2r[c];
        }
        float pv = wave_reduce(pa);
        if (lane == 0) P.pr[r][wv] = pv;
      }
      __syncthreads();
      if (tid < 16) {
        float tot = P.pr[tid][0] + P.pr[tid][1] + P.pr[tid][2] + P.pr[tid][3] +
                    pi_b2[0];
        pi[row0 + tid] = 1.f / (1.f + expf(-tot));
      }
    }
  }
  gridbar(bar + 0 * 256, nBlk, bid);

  // ========= P1: K_eps rows (bf16) + rowsum -> v ==========================
  {
    int nItems = N / 4;
    for (int item = bid; item < nItems; item += nBlk) {
      __syncthreads();
      int i0 = item * 4;
      float a[4][16], si[4];
#pragma unroll
      for (int r = 0; r < 4; ++r) {
        const float* ap = xp + (size_t)(i0 + r) * 16;
#pragma unroll
        for (int t = 0; t < 16; ++t) a[r][t] = ap[t];
        si[r] = s[i0 + r];
      }
      const float cc = 1.f / (4.f * EPSILON);
      float qa[4] = {0.f, 0.f, 0.f, 0.f};
      for (int it = 0; it < N / 512; ++it) {
        int j = it * 512 + tid * 2;
        const float4* bp = (const float4*)(xp + (size_t)j * 16);
        float4 b0 = bp[0], b1 = bp[1], b2 = bp[2], b3 = bp[3];
        float4 c0 = bp[4], c1 = bp[5], c2 = bp[6], c3 = bp[7];
        float bvv[16] = {b0.x, b0.y, b0.z, b0.w, b1.x, b1.y, b1.z, b1.w,
                         b2.x, b2.y, b2.z, b2.w, b3.x, b3.y, b3.z, b3.w};
        float cvv[16] = {c0.x, c0.y, c0.z, c0.w, c1.x, c1.y, c1.z, c1.w,
                         c2.x, c2.y, c2.z, c2.w, c3.x, c3.y, c3.z, c3.w};
        float sj0 = s[j], sj1 = s[j + 1];
#pragma unroll
        for (int r = 0; r < 4; ++r) {
          float d0 = 0.f, d1 = 0.f;
#pragma unroll
          for (int t = 0; t < 16; ++t) {
            d0 += a[r][t] * bvv[t];
            d1 += a[r][t] * cvv[t];
          }
          float k0 = __expf(-cc * (si[r] + sj0 - 2.f * d0));
          float k1 = __expf(-cc * (si[r] + sj1 - 2.f * d1));
          *(unsigned int*)(Kb + (size_t)(i0 + r) * N + j) = pack2(k0, k1);
          qa[r] += k0 + k1;
        }
      }
#pragma unroll
      for (int r = 0; r < 4; ++r) {
        float t = wave_reduce(qa[r]);
        if (lane == 0) qs[r][wv] = t;
      }
      __syncthreads();
      if (tid < 4) {
        float tot = qs[tid][0] + qs[tid][1] + qs[tid][2] + qs[tid][3];
        v[i0 + tid] = pi[i0 + tid] / tot;
      }
    }
  }
  gridbar(bar + 1 * 256, nBlk, bid);

  // ========= P2: dv (wave-per-row) + xvbT transpose tiles =================
  {
    int nDv = N / 4;
    int cols = D / 64;
    int nXT = cols * (N / 64);
    for (int item = bid; item < nDv + nXT; item += nBlk) {
      if (item < nDv) {
        int i = item * 4 + wv;
        const unsigned short* kr = Kb + (size_t)i * N;
        float acc = 0.f;
        for (int c0 = lane * 8; c0 < N; c0 += 512) {
          uint4 kv = *(const uint4*)(kr + c0);
          float4 va = *(const float4*)(v + c0);
          float4 vb = *(const float4*)(v + c0 + 4);
          unsigned int u;
          u = kv.x;
          acc += __uint_as_float(u << 16) * va.x +
                 __uint_as_float(u & 0xffff0000u) * va.y;
          u = kv.y;
          acc += __uint_as_float(u << 16) * va.z +
                 __uint_as_float(u & 0xffff0000u) * va.w;
          u = kv.z;
          acc += __uint_as_float(u << 16) * vb.x +
                 __uint_as_float(u & 0xffff0000u) * vb.y;
          u = kv.w;
          acc += __uint_as_float(u << 16) * vb.z +
                 __uint_as_float(u & 0xffff0000u) * vb.w;
        }
        acc = wave_reduce(acc);
        if (lane == 0) dv[i] = acc + 1e-5f;
      } else {  // 64x64: xvbT[d][j] = bf16(v[j]*x[j][d])
        int t = item - nDv;
        __syncthreads();
        unsigned short(*tile)[65] = (unsigned short(*)[65])pool;
        int c0 = (t % cols) * 64, r0 = (t / cols) * 64;
#pragma unroll
        for (int i = 0; i < 16; ++i) {
          int rr = wv * 16 + i;
          tile[rr][lane] =
              f2bf(v[r0 + rr] * x[(size_t)(r0 + rr) * D + c0 + lane]);
        }
        __syncthreads();
#pragma unroll
        for (int i = 0; i < 16; ++i) {
          int rr = wv * 16 + i;
          xvbT[(size_t)(c0 + rr) * N + r0 + lane] = tile[lane][rr];
        }
      }
    }
  }
  gridbar(bar + 2 * 256, nBlk, bid);

  // ========= P3: Y = Kb @ xvbT^T; Z = bf16(c2*x + (c3b/dv)*Y) =============
  // Double-buffered K-loop (stage k+1 while computing k; one barrier/step),
  // XCD-chunked tile order (bid&7 = XCD; contiguous item chunk per XCD).
  {
    float dtv = dtp[0];
    float c2 = (1.f - ALPHA) * (1.f - 2.f * dtv);
    float c3b = (1.f - ALPHA) * 2.f * dtv / EPSILON;
    unsigned short* As0 = (unsigned short*)pool;
    unsigned short* Bs0 = As0 + 64 * 128;
    unsigned short* As1 = Bs0 + 64 * 128;
    unsigned short* Bs1 = As1 + 64 * 128;
    int tilesX = D / 64;
    int nT = tilesX * (N / 64);
    int qch = (nT + 7) >> 3;  // items per XCD chunk
    int ln = lane & 15, quad = lane >> 4;
    int mh = (wv & 1) * 32, nh = (wv >> 1) * 32;
    int srow = wv * 4 + quad;
    int swz = (ln ^ srow) * 8;
    for (int raw = bid; raw < (qch << 3); raw += nBlk) {
      int item = (raw & 7) * qch + (raw >> 3);
      if (item >= nT) continue;
      int row0 = (item / tilesX) * 64, col0 = (item % tilesX) * 64;
      const unsigned short* gA = Kb + (size_t)(row0 + srow) * N + swz;
      const unsigned short* gB = xvbT + (size_t)(col0 + srow) * N + swz;
      f32x4 acc[2][2] = {};
      // prologue: stage k0=0 into buf0
#pragma unroll
      for (int q = 0; q < 4; ++q) {
        async16(gA + (size_t)q * 16 * N, As0 + (q * 16 + wv * 4) * 128);
        async16(gB + (size_t)q * 16 * N, Bs0 + (q * 16 + wv * 4) * 128);
      }
      __syncthreads();
      int cur = 0;
      for (int k0 = 0; k0 < N; k0 += 128) {
        unsigned short* Asc = cur ? As1 : As0;
        unsigned short* Bsc = cur ? Bs1 : Bs0;
        if (k0 + 128 < N) {  // stage next tile into the other buffer
          unsigned short* Asn = cur ? As0 : As1;
          unsigned short* Bsn = cur ? Bs0 : Bs1;
#pragma unroll
          for (int q = 0; q < 4; ++q) {
            async16(gA + (size_t)q * 16 * N + k0 + 128,
                    Asn + (q * 16 + wv * 4) * 128);
            async16(gB + (size_t)q * 16 * N + k0 + 128,
                    Bsn + (q * 16 + wv * 4) * 128);
          }
        }
#pragma unroll
        for (int ks = 0; ks < 4; ++ks) {
          bf16x8 bfr[2], afr[2];
#pragma unroll
          for (int nt = 0; nt < 2; ++nt) {
            int r = nh + nt * 16 + ln;
            int cix = (ks * 4 + quad) ^ (r & 15);
            bfr[nt] = *(const bf16x8*)&Bsc[r * 128 + cix * 8];
          }
#pragma unroll
          for (int mt = 0; mt < 2; ++mt) {
            int r = mh + mt * 16 + ln;
            int cix = (ks * 4 + quad) ^ (r & 15);
            afr[mt] = *(const bf16x8*)&Asc[r * 128 + cix * 8];
          }
#pragma unroll
          for (int mt = 0; mt < 2; ++mt)
#pragma unroll
            for (int nt = 0; nt < 2; ++nt)
              acc[mt][nt] = __builtin_amdgcn_mfma_f32_16x16x32_bf16(
                  afr[mt], bfr[nt], acc[mt][nt], 0, 0, 0);
        }
        __syncthreads();  // drains next-stage vmcnt; protects buf reuse
        cur ^= 1;
      }
#pragma unroll
      for (int mt = 0; mt < 2; ++mt)
#pragma unroll
        for (int nt = 0; nt < 2; ++nt) {
          int col = col0 + nh + nt * 16 + ln;
#pragma unroll
          for (int r = 0; r < 4; ++r) {
            int row = row0 + mh + mt * 16 + quad * 4 + r;
            float c3 = c3b / dv[row];
            Z[(size_t)row * D + col] =
                f2bf(c2 * x[(size_t)row * D + col] + c3 * acc[mt][nt][r]);
          }
        }
    }
  }
  gridbar(bar + 3 * 256, nBlk, bid);

  // ========= P4: pre = ALPHA*x + Z @ fwTb^T + cb*fb ======================
  {
    float dtv = dtp[0];
    float cb = (1.f - ALPHA) * (1.f - 2.f * dtv) +
               (1.f - ALPHA) * 2.f * dtv / EPSILON;
    unsigned short* As0 = (unsigned short*)pool;
    unsigned short* Bs0 = As0 + 64 * 128;
    unsigned short* As1 = Bs0 + 64 * 128;
    unsigned short* Bs1 = As1 + 64 * 128;
    int tilesX = D / 64;
    int nT = tilesX * (N / 64);
    int qch = (nT + 7) >> 3;
    int ln = lane & 15, quad = lane >> 4;
    int mh = (wv & 1) * 32, nh = (wv >> 1) * 32;
    int srow = wv * 4 + quad;
    int swz = (ln ^ srow) * 8;
    for (int raw = bid; raw < (qch << 3); raw += nBlk) {
      int item = (raw & 7) * qch + (raw >> 3);
      if (item >= nT) continue;
      int row0 = (item / tilesX) * 64, col0 = (item % tilesX) * 64;
      const unsigned short* gA = Z + (size_t)(row0 + srow) * D + swz;
      const unsigned short* gB = fwTb + (size_t)(col0 + srow) * D + swz;
      f32x4 acc[2][2] = {};
#pragma unroll
      for (int q = 0; q < 4; ++q) {
        async16(gA + (size_t)q * 16 * D, As0 + (q * 16 + wv * 4) * 128);
        async16(gB + (size_t)q * 16 * D, Bs0 + (q * 16 + wv * 4) * 128);
      }
      __syncthreads();
      int cur = 0;
      for (int k0 = 0; k0 < D; k0 += 128) {
        unsigned short* Asc = cur ? As1 : As0;
        unsigned short* Bsc = cur ? Bs1 : Bs0;
        if (k0 + 128 < D) {
          unsigned short* Asn = cur ? As0 : As1;
          unsigned short* Bsn = cur ? Bs0 : Bs1;
#pragma unroll
          for (int q = 0; q < 4; ++q) {
            async16(gA + (size_t)q * 16 * D + k0 + 128,
                    Asn + (q * 16 + wv * 4) * 128);
            async16(gB + (size_t)q * 16 * D + k0 + 128,
                    Bsn + (q * 16 + wv * 4) * 128);
          }
        }
#pragma unroll
        for (int ks = 0; ks < 4; ++ks) {
          bf16x8 bfr[2], afr[2];
#pragma unroll
          for (int nt = 0; nt < 2; ++nt) {
            int r = nh + nt * 16 + ln;
            int cix = (ks * 4 + quad) ^ (r & 15);
            bfr[nt] = *(const bf16x8*)&Bsc[r * 128 + cix * 8];
          }
#pragma unroll
          for (int mt = 0; mt < 2; ++mt) {
            int r = mh + mt * 16 + ln;
            int cix = (ks * 4 + quad) ^ (r & 15);
            afr[mt] = *(const bf16x8*)&Asc[r * 128 + cix * 8];
          }
#pragma unroll
          for (int mt = 0; mt < 2; ++mt)
#pragma unroll
            for (int nt = 0; nt < 2; ++nt)
              acc[mt][nt] = __builtin_amdgcn_mfma_f32_16x16x32_bf16(
                  afr[mt], bfr[nt], acc[mt][nt], 0, 0, 0);
        }
        __syncthreads();
        cur ^= 1;
      }
#pragma unroll
      for (int mt = 0; mt < 2; ++mt)
#pragma unroll
        for (int nt = 0; nt < 2; ++nt) {
          int col = col0 + nh + nt * 16 + ln;
          float bv = cb * fb[col];
#pragma unroll
          for (int r = 0; r < 4; ++r) {
            int row = row0 + mh + mt * 16 + quad * 4 + r;
            size_t idx = (size_t)row * D + col;
            out[idx] = ALPHA * x[idx] + acc[mt][nt][r] + bv;
          }
        }
    }
  }
  gridbar(bar + 4 * 256, nBlk, bid);

  // ========= P5: in-place row LayerNorm (1 wave / row) ====================
  {
    int nItems = N / 4;
    for (int item = bid; item < nItems; item += nBlk) {
      int i = item * 4 + wv;
      float4 vv[3];  // D == 768
      float sum = 0.f;
#pragma unroll
      for (int t = 0; t < 3; ++t) {
        vv[t] = *(const float4*)(out + (size_t)i * D + lane * 4 + t * 256);
        sum += vv[t].x + vv[t].y + vv[t].z + vv[t].w;
      }
      float mu = wave_reduce(sum) / (float)D;
      float sq = 0.f;
#pragma unroll
      for (int t = 0; t < 3; ++t) {
        float dx = vv[t].x - mu, dy = vv[t].y - mu;
        float dz = vv[t].z - mu, dw = vv[t].w - mu;
        sq += dx * dx + dy * dy + dz * dz + dw * dw;
      }
      float var = wave_reduce(sq) / (float)D;
      float rs = rsqrtf(var + LN_EPS);
#pragma unroll
      for (int t = 0; t < 3; ++t) {
        int d0 = lane * 4 + t * 256;
        float4 gv = *(const float4*)(ln2_g + d0);
        float4 bv = *(const float4*)(ln2_b + d0);
        float4 o;
        o.x = (vv[t].x - mu) * rs * gv.x + bv.x;
        o.y = (vv[t].y - mu) * rs * gv.y + bv.y;
        o.z = (vv[t].z - mu) * rs * gv.z + bv.z;
        o.w = (vv[t].w - mu) * rs * gv.w + bv.w;
        *(float4*)(out + (size_t)i * D + d0) = o;
      }
    }
  }
}

// ===================== legacy 6-kernel fallback path =======================

__global__ __launch_bounds__(256) void k_proj(
    const float* __restrict__ x, const float* __restrict__ proj_w,
    const float* __restrict__ proj_b, const float* __restrict__ ln1_g,
    const float* __restrict__ ln1_b, const float* __restrict__ pi_w1,
    const float* __restrict__ pi_b1, const float* __restrict__ pi_w2,
    const float* __restrict__ pi_b2, const float* __restrict__ fw,
    unsigned short* __restrict__ fwTb, float* __restrict__ xp,
    float* __restrict__ s, float* __restrict__ pi, int N, int D) {
  __shared__ float xs[16][68];
  __shared__ float ws[64][20];
  __shared__ float ysh[16][17];
  __shared__ float xps[16][16];
  __shared__ float pr[16][4];
  int tid = threadIdx.x;
  int nProj = N / 16;
  if (blockIdx.x >= (unsigned)nProj) {
    unsigned short(*tile)[33] = (unsigned short(*)[33])&ws[0][0];
    int t = blockIdx.x - nProj;
    int tx = tid & 31, ty = tid >> 5;
    int cols = D / 32;
    int c0 = (t % cols) * 32, r0 = (t / cols) * 32;
#pragma unroll
    for (int i = 0; i < 4; ++i) {
      int r = r0 + ty + i * 8;
      tile[ty + i * 8][tx] = f2bf(fw[(size_t)r * D + c0 + tx]);
    }
    __syncthreads();
#pragma unroll
    for (int i = 0; i < 4; ++i) {
      int cc = c0 + ty + i * 8;
      fwTb[(size_t)cc * D + r0 + tx] = tile[tx][ty + i * 8];
    }
    return;
  }
  int row0 = blockIdx.x * 16;
  int row = tid >> 4, l = tid & 15;
  int lane = tid & 63, w = tid >> 6;
  int skc = (tid & 15) * 4;
  int wk = tid >> 2, wl = (tid & 3) * 4;
  float acc = 0.f;
  for (int k0 = 0; k0 < D; k0 += 64) {
    float4 xv = *(const float4*)(x + (size_t)(row0 + row) * D + k0 + skc);
    float4 wv = *(const float4*)(proj_w + (size_t)(k0 + wk) * 16 + wl);
    __syncthreads();
    *(float4*)&xs[row][skc] = xv;
    *(float4*)&ws[wk][wl] = wv;
    __syncthreads();
#pragma unroll
    for (int kk = 0; kk < 64; kk += 4) {
      float4 a4 = *(const float4*)&xs[row][kk];
      acc += a4.x * ws[kk + 0][l];
      acc += a4.y * ws[kk + 1][l];
      acc += a4.z * ws[kk + 2][l];
      acc += a4.w * ws[kk + 3][l];
    }
  }
  float y = acc + proj_b[l];
  ysh[row][l] = y;
  __syncthreads();
  float mu = 0.f;
#pragma unroll
  for (int t = 0; t < 16; ++t) mu += ysh[row][t];
  mu *= (1.f / 16.f);
  float var = 0.f;
#pragma unroll
  for (int t = 0; t < 16; ++t) { float d2 = ysh[row][t] - mu; var += d2 * d2; }
  var *= (1.f / 16.f);
  float rstd = rsqrtf(var + LN_EPS);
  float xpv = fmaxf((y - mu) * rstd * ln1_g[l] + ln1_b[l], 0.f);
  xps[row][l] = xpv;
  xp[(size_t)(row0 + row) * 16 + l] = xpv;
  float sq = xpv * xpv;
  sq += __shfl_xor(sq, 8, 64);
  sq += __shfl_xor(sq, 4, 64);
  sq += __shfl_xor(sq, 2, 64);
  sq += __shfl_xor(sq, 1, 64);
  if ((lane & 15) == 0) s[row0 + row] = sq;
  __syncthreads();
  float w1r[3][16], b1r[3], w2r[3];
#pragma unroll
  for (int c = 0; c < 3; ++c) {
    int d0 = tid + c * 256;
    b1r[c] = pi_b1[d0];
    w2r[c] = pi_w2[d0];
#pragma unroll
    for (int t = 0; t < 16; ++t) w1r[c][t] = pi_w1[(size_t)t * D + d0];
  }
#pragma unroll
  for (int r = 0; r < 16; ++r) {
    float xv[16];
#pragma unroll
    for (int t4 = 0; t4 < 4; ++t4) {
      float4 xq = *(const float4*)&xps[r][t4 * 4];
      xv[t4 * 4 + 0] = xq.x; xv[t4 * 4 + 1] = xq.y;
      xv[t4 * 4 + 2] = xq.z; xv[t4 * 4 + 3] = xq.w;
    }
    float pa = 0.f;
#pragma unroll
    for (int c = 0; c < 3; ++c) {
      float h = b1r[c];
#pragma unroll
      for (int t = 0; t < 16; ++t) h += xv[t] * w1r[c][t];
      h = fmaxf(h, 0.f);
      pa += h * w2r[c];
    }
    float pv = wave_reduce(pa);
    if (lane == 0) pr[r][w] = pv;
  }
  __syncthreads();
  if (tid < 16) {
    float tot = pr[tid][0] + pr[tid][1] + pr[tid][2] + pr[tid][3] + pi_b2[0];
    pi[row0 + tid] = 1.f / (1.f + expf(-tot));
  }
}

__global__ __launch_bounds__(256) void k_keps(
    const float* __restrict__ xp, const float* __restrict__ s,
    const float* __restrict__ pi, unsigned short* __restrict__ Kb,
    float* __restrict__ v, int N) {
  __shared__ float qs[4][4];
  int i0 = blockIdx.x * 4;
  int tid = threadIdx.x, lane = tid & 63, w = tid >> 6;
  float a[4][16], si[4];
#pragma unroll
  for (int r = 0; r < 4; ++r) {
    const float* ap = xp + (size_t)(i0 + r) * 16;
#pragma unroll
    for (int t = 0; t < 16; ++t) a[r][t] = ap[t];
    si[r] = s[i0 + r];
  }
  const float c = 1.f / (4.f * EPSILON);
  float qa[4] = {0.f, 0.f, 0.f, 0.f};
  for (int it = 0; it < N / 512; ++it) {
    int j = it * 512 + tid * 2;
    const float4* bp = (const float4*)(xp + (size_t)j * 16);
    float4 b0 = bp[0], b1 = bp[1], b2 = bp[2], b3 = bp[3];
    float4 c0 = bp[4], c1 = bp[5], c2 = bp[6], c3 = bp[7];
    float bv[16] = {b0.x, b0.y, b0.z, b0.w, b1.x, b1.y, b1.z, b1.w,
                    b2.x, b2.y, b2.z, b2.w, b3.x, b3.y, b3.z, b3.w};
    float cv[16] = {c0.x, c0.y, c0.z, c0.w, c1.x, c1.y, c1.z, c1.w,
                    c2.x, c2.y, c2.z, c2.w, c3.x, c3.y, c3.z, c3.w};
    float sj0 = s[j], sj1 = s[j + 1];
#pragma unroll
    for (int r = 0; r < 4; ++r) {
      float d0 = 0.f, d1 = 0.f;
#pragma unroll
      for (int t = 0; t < 16; ++t) { d0 += a[r][t] * bv[t]; d1 += a[r][t] * cv[t]; }
      float k0 = __expf(-c * (si[r] + sj0 - 2.f * d0));
      float k1 = __expf(-c * (si[r] + sj1 - 2.f * d1));
      *(unsigned int*)(Kb + (size_t)(i0 + r) * N + j) = pack2(k0, k1);
      qa[r] += k0 + k1;
    }
  }
#pragma unroll
  for (int r = 0; r < 4; ++r) {
    float t = wave_reduce(qa[r]);
    if (lane == 0) qs[r][w] = t;
  }
  __syncthreads();
  if (tid < 4) {
    float tot = qs[tid][0] + qs[tid][1] + qs[tid][2] + qs[tid][3];
    v[i0 + tid] = pi[i0 + tid] / tot;
  }
}

__global__ __launch_bounds__(256) void k_prep(
    const unsigned short* __restrict__ Kb, const float* __restrict__ v,
    float* __restrict__ dv, const float* __restrict__ x,
    unsigned short* __restrict__ xvbT, int N, int D) {
  __shared__ float sh[544];
  int bid = blockIdx.x, tid = threadIdx.x;
  if (bid < N) {
    int i = bid;
    float acc = 0.f;
    for (int j8 = tid * 8; j8 < N; j8 += 256 * 8) {
      uint4 kv4 = *(const uint4*)(Kb + (size_t)i * N + j8);
      float4 va = *(const float4*)(v + j8);
      float4 vb = *(const float4*)(v + j8 + 4);
      unsigned int u;
      u = kv4.x;
      acc += __uint_as_float(u << 16) * va.x + __uint_as_float(u & 0xffff0000u) * va.y;
      u = kv4.y;
      acc += __uint_as_float(u << 16) * va.z + __uint_as_float(u & 0xffff0000u) * va.w;
      u = kv4.z;
      acc += __uint_as_float(u << 16) * vb.x + __uint_as_float(u & 0xffff0000u) * vb.y;
      u = kv4.w;
      acc += __uint_as_float(u << 16) * vb.z + __uint_as_float(u & 0xffff0000u) * vb.w;
    }
    float tot = blk_reduce_sum(acc, sh);
    if (tid == 0) dv[i] = tot + 1e-5f;
  } else {
    int t = bid - N;
    unsigned short(*tile)[33] = (unsigned short(*)[33])sh;
    int tx = tid & 31, ty = tid >> 5;
    int cols = D / 32;
    int c0 = (t % cols) * 32;
    int r0 = (t / cols) * 32;
#pragma unroll
    for (int i = 0; i < 4; ++i) {
      int r = r0 + ty + i * 8;
      tile[ty + i * 8][tx] = f2bf(v[r] * x[(size_t)r * D + c0 + tx]);
    }
    __syncthreads();
#pragma unroll
    for (int i = 0; i < 4; ++i) {
      int cc = c0 + ty + i * 8;
      xvbT[(size_t)cc * N + r0 + tx] = tile[tx][ty + i * 8];
    }
  }
}

#define GEMM_KLOOP(Aptr, Bptr, Kdim)                                          \
  int tid = threadIdx.x;                                                      \
  int w = tid >> 6, l = tid & 63;                                             \
  int ln = l & 15, quad = l >> 4;                                             \
  int mh = (w & 1) * 32, nh = (w >> 1) * 32;                                  \
  int row0 = blockIdx.y * 64, col0 = blockIdx.x * 64;                         \
  int srow = w * 4 + (l >> 4);                                                \
  int swz = ((l & 15) ^ srow) * 8;                                            \
  const unsigned short* gA = Aptr + (size_t)(row0 + srow) * Kdim + swz;       \
  const unsigned short* gB = Bptr + (size_t)(col0 + srow) * Kdim + swz;       \
  f32x4 acc[2][2] = {};                                                       \
  for (int k0 = 0; k0 < Kdim; k0 += 128) {                                    \
    __syncthreads();                                                          \
    _Pragma("unroll")                                                         \
    for (int q = 0; q < 4; ++q) {                                             \
      async16(gA + (size_t)q * 16 * Kdim + k0, As + (q * 16 + w * 4) * 128);  \
      async16(gB + (size_t)q * 16 * Kdim + k0, Bs + (q * 16 + w * 4) * 128);  \
    }                                                                         \
    __syncthreads();                                                          \
    _Pragma("unroll")                                                         \
    for (int ks = 0; ks < 4; ++ks) {                                          \
      bf16x8 bfr[2], afr[2];                                                  \
      _Pragma("unroll")                                                       \
      for (int nt = 0; nt < 2; ++nt) {                                        \
        int r = nh + nt * 16 + ln;                                            \
        int cix = (ks * 4 + quad) ^ (r & 15);                                 \
        bfr[nt] = *(const bf16x8*)&Bs[r * 128 + cix * 8];                     \
      }                                                                       \
      _Pragma("unroll")                                                       \
      for (int mt = 0; mt < 2; ++mt) {                                        \
        int r = mh + mt * 16 + ln;                                            \
        int cix = (ks * 4 + quad) ^ (r & 15);                                 \
        afr[mt] = *(const bf16x8*)&As[r * 128 + cix * 8];                     \
      }                                                                       \
      _Pragma("unroll")                                                       \
      for (int mt = 0; mt < 2; ++mt)                                          \
        _Pragma("unroll")                                                     \
        for (int nt = 0; nt < 2; ++nt)                                        \
          acc[mt][nt] = __builtin_amdgcn_mfma_f32_16x16x32_bf16(              \
              afr[mt], bfr[nt], acc[mt][nt], 0, 0, 0);                        \
    }                                                                         \
  }

__global__ __launch_bounds__(256) void k_gemmA(
    const unsigned short* __restrict__ A, const unsigned short* __restrict__ Bt,
    const float* __restrict__ x, const float* __restrict__ dv,
    const float* __restrict__ dtp, unsigned short* __restrict__ Z,
    int M, int N, int K) {
  __shared__ unsigned short As[64 * 128];
  __shared__ unsigned short Bs[64 * 128];
  GEMM_KLOOP(A, Bt, K)
  float dtv = dtp[0];
  float c2 = (1.f - ALPHA) * (1.f - 2.f * dtv);
  float c3b = (1.f - ALPHA) * 2.f * dtv / EPSILON;
#pragma unroll
  for (int mt = 0; mt < 2; ++mt)
#pragma unroll
    for (int nt = 0; nt < 2; ++nt) {
      int col = col0 + nh + nt * 16 + ln;
#pragma unroll
      for (int r = 0; r < 4; ++r) {
        int row = row0 + mh + mt * 16 + quad * 4 + r;
        float c3 = c3b / dv[row];
        Z[(size_t)row * N + col] =
            f2bf(c2 * x[(size_t)row * N + col] + c3 * acc[mt][nt][r]);
      }
    }
}

__global__ __launch_bounds__(256) void k_gemmB(
    const unsigned short* __restrict__ A, const unsigned short* __restrict__ Bt,
    const float* __restrict__ x, const float* __restrict__ bias,
    const float* __restrict__ dtp, float* __restrict__ out,
    int M, int N, int K) {
  __shared__ unsigned short As[64 * 128];
  __shared__ unsigned short Bs[64 * 128];
  GEMM_KLOOP(A, Bt, K)
  float dtv = dtp[0];
  float cb = (1.f - ALPHA) * (1.f - 2.f * dtv) +
             (1.f - ALPHA) * 2.f * dtv / EPSILON;
#pragma unroll
  for (int mt = 0; mt < 2; ++mt)
#pragma unroll
    for (int nt = 0; nt < 2; ++nt) {
      int col = col0 + nh + nt * 16 + ln;
      float bv = cb * bias[col];
#pragma unroll
      for (int r = 0; r < 4; ++r) {
        int row = row0 + mh + mt * 16 + quad * 4 + r;
        size_t idx = (size_t)row * N + col;
        out[idx] = ALPHA * x[idx] + acc[mt][nt][r] + bv;
      }
    }
}

__global__ __launch_bounds__(256) void k_ln_rows(
    float* __restrict__ out, const float* __restrict__ g,
    const float* __restrict__ b, int D) {
  __shared__ float red[4];
  int i = blockIdx.x, tid = threadIdx.x;
  float vv[4];
  int nt = D / 256;
  float sum = 0.f;
  for (int t = 0; t < nt; ++t) {
    vv[t] = out[(size_t)i * D + tid + t * 256];
    sum += vv[t];
  }
  float mu = blk_reduce_sum(sum, red) / (float)D;
  float sq = 0.f;
  for (int t = 0; t < nt; ++t) { float d2 = vv[t] - mu; sq += d2 * d2; }
  float var = blk_reduce_sum(sq, red) / (float)D;
  float rs = rsqrtf(var + LN_EPS);
  for (int t = 0; t < nt; ++t) {
    int d0 = tid + t * 256;
    out[(size_t)i * D + d0] = (vv[t] - mu) * rs * g[d0] + b[d0];
  }
}

extern "C" void kernel_launch(void* const* d_in, const int* in_sizes, int n_in,
                              void* d_out, int out_size, void* d_ws, size_t ws_size,
                              hipStream_t stream) {
  const float* x = (const float*)d_in[0];
  const float* proj_w = (const float*)d_in[1];
  const float* proj_b = (const float*)d_in[2];
  const float* ln1_g = (const float*)d_in[3];
  const float* ln1_b = (const float*)d_in[4];
  const float* pi_w1 = (const float*)d_in[5];
  const float* pi_b1 = (const float*)d_in[6];
  const float* pi_w2 = (const float*)d_in[7];
  const float* pi_b2 = (const float*)d_in[8];
  const float* dt = (const float*)d_in[9];
  const float* f_w = (const float*)d_in[10];
  const float* f_b = (const float*)d_in[11];
  const float* ln2_g = (const float*)d_in[12];
  const float* ln2_b = (const float*)d_in[13];
  float* out = (float*)d_out;

  int D = in_sizes[11];      // 768
  int N = in_sizes[0] / D;   // 2048

  unsigned short* Kb = (unsigned short*)d_ws;                   // N*N bf16
  unsigned short* xvbT = Kb + (size_t)N * N;                    // D*N bf16
  unsigned short* fwTb = xvbT + (size_t)D * N;                  // D*D bf16
  unsigned short* Z = fwTb + (size_t)D * D;                     // N*D bf16
  float* xp = (float*)(Z + (size_t)N * D);                      // N*16
  float* s = xp + (size_t)N * 16;                               // N
  float* pi = s + N;                                            // N
  float* v = pi + N;                                            // N
  float* dv = v + N;                                            // N
  // barrier counters: aligned past the float scratch.
  // 5 barriers x 8 lines x 32 ints = 1280 ints (5 KB)
  char* dvEnd = (char*)(dv + N);
  int* bar = (int*)((((uintptr_t)dvEnd) + 255) & ~(uintptr_t)255);

  // ---- preferred path: persistent kernel + custom grid barriers ----
  bool ok = false;
  int maxBlk = 0;
  hipError_t qerr =
      hipOccupancyMaxActiveBlocksPerMultiprocessor(&maxBlk, k_mega2, 256, 0);
  if (qerr == hipSuccess && maxBlk > 0) {
    int dev = 0, numCU = 256;
    hipGetDevice(&dev);
    hipDeviceGetAttribute(&numCU, hipDeviceAttributeMultiprocessorCount, dev);
    long cap = (long)maxBlk * (long)numCU;
    int grid = (int)(cap < 512 ? cap : 512);
    if (grid >= 64) {
      hipMemsetAsync(bar, 0, 5 * 256 * sizeof(int), stream);
      k_mega2<<<grid, 256, 0, stream>>>(
          x, proj_w, proj_b, ln1_g, ln1_b, pi_w1, pi_b1, pi_w2, pi_b2, dt,
          f_w, f_b, ln2_g, ln2_b, Kb, xvbT, fwTb, Z, xp, s, pi, v, dv, out,
          bar, N, D);
      ok = true;
    }
  }

  if (!ok) {
    // ---- fallback: proven 6-kernel pipeline ----
    int fwB = (D / 32) * (D / 32);
    int xvtB = (D / 32) * (N / 32);
    k_proj<<<N / 16 + fwB, 256, 0, stream>>>(x, proj_w, proj_b, ln1_g, ln1_b,
                                             pi_w1, pi_b1, pi_w2, pi_b2, f_w,
                                             fwTb, xp, s, pi, N, D);
    k_keps<<<N / 4, 256, 0, stream>>>(xp, s, pi, Kb, v, N);
    k_prep<<<N + xvtB, 256, 0, stream>>>(Kb, v, dv, x, xvbT, N, D);
    k_gemmA<<<dim3(D / 64, N / 64), 256, 0, stream>>>(Kb, xvbT, x, dv, dt, Z,
                                                      N, D, N);
    k_gemmB<<<dim3(D / 64, N / 64), 256, 0, stream>>>(Z, fwTb, x, f_b, dt, out,
                                                      N, D, D);
    k_ln_rows<<<N, 256, 0, stream>>>(out, ln2_g, ln2_b, D);
  }
}